// Round 1
// baseline (293.445 us; speedup 1.0000x reference)
//
#include <hip/hip_runtime.h>

// Problem constants (from reference): L=512, B=2, D=256, C=128, O=64
#define LL 512
#define BB 2
#define DD 256
#define CC 128
#define OO 64

#define MT 128   // m-rows per main-kernel block
#define KT 32    // k-chunk staged in LDS

__device__ __forceinline__ float wave_reduce_sum(float v) {
#pragma unroll
    for (int off = 32; off > 0; off >>= 1)
        v += __shfl_down(v, off, 64);
    return v;
}

// One block per (b, l): LayerNorm of x[l,b,:], then
//   a[c] = LN(x) . w1[:,c] + b1[c]
//   b[c] = LN(x) . w2[:,c] + b2[c]
//   a4b3[o] = a . w4[:,o] + b3[o]     (b3 folded here)
//   b4[o]   = b . w4[:,o]
__global__ __launch_bounds__(256) void prep_kernel(
    const float* __restrict__ x,
    const float* __restrict__ gamma,
    const float* __restrict__ beta,
    const float* __restrict__ w1, const float* __restrict__ b1,
    const float* __restrict__ w2, const float* __restrict__ b2,
    const float* __restrict__ w4, const float* __restrict__ b3,
    float* __restrict__ a_ws, float* __restrict__ b_ws,
    float* __restrict__ a4b3_ws, float* __restrict__ b4_ws)
{
    const int blk = blockIdx.x;           // b*LL + l
    const int b = blk >> 9;
    const int l = blk & (LL - 1);
    const int t = threadIdx.x;            // 0..255 == d index

    __shared__ float ylds[DD];
    __shared__ float ab[2 * CC];
    __shared__ float red[8];

    // x is (L, B, D)
    float xv = x[(l * BB + b) * DD + t];
    float s = wave_reduce_sum(xv);
    if ((t & 63) == 0) red[t >> 6] = s;
    __syncthreads();
    float mu = (red[0] + red[1] + red[2] + red[3]) * (1.0f / DD);
    float xc = xv - mu;
    float s2 = wave_reduce_sum(xc * xc);
    if ((t & 63) == 0) red[4 + (t >> 6)] = s2;   // disjoint slots: no WAR on red[0..3]
    __syncthreads();
    float var = (red[4] + red[5] + red[6] + red[7]) * (1.0f / DD);
    float y = xc * rsqrtf(var + 1e-5f) * gamma[t] + beta[t];
    ylds[t] = y;
    __syncthreads();

    // a (threads 0..127) and b (threads 128..255) projections
    {
        const int c = t & (CC - 1);
        const float* w = (t < CC) ? w1 : w2;
        float acc = (t < CC) ? b1[c] : b2[c];
#pragma unroll 8
        for (int d = 0; d < DD; ++d)
            acc = fmaf(ylds[d], w[d * CC + c], acc);   // coalesced w column reads
        ab[t] = acc;
        float* dst = (t < CC) ? a_ws : b_ws;
        dst[(b * LL + l) * CC + c] = acc;
    }
    __syncthreads();

    // a4+b3 (threads 0..63) and b4 (threads 64..127)
    if (t < 2 * OO) {
        const int o = t & (OO - 1);
        const float* src = (t < OO) ? ab : (ab + CC);
        float acc = (t < OO) ? b3[o] : 0.0f;
#pragma unroll 8
        for (int c = 0; c < CC; ++c)
            acc = fmaf(src[c], w4[c * OO + o], acc);
        float* dst = (t < OO) ? a4b3_ws : b4_ws;
        dst[(b * LL + l) * OO + o] = acc;
    }
}

// One block per (b, l, m-chunk of 128). Computes
//   out[b,l,m,o] = sum_c b_act[b,m,c] * (a[b,l,c]*w3[c,o]) + a4b3[b,l,o] - b4[b,m,o]
// via W_l in LDS + register-tiled (4m x 8o) fp32 GEMM.
__global__ __launch_bounds__(256) void main_kernel(
    const float* __restrict__ a_ws, const float* __restrict__ b_ws,
    const float* __restrict__ a4b3_ws, const float* __restrict__ b4_ws,
    const float* __restrict__ w3,
    float* __restrict__ out)
{
    const int bid = blockIdx.x;          // b*2048 + l*4 + mc
    const int mc = bid & 3;
    const int l  = (bid >> 2) & (LL - 1);
    const int b  = bid >> 11;
    const int t  = threadIdx.x;

    __shared__ float wl[CC * OO];            // 32 KB: W_l[c][o]
    __shared__ float btile[MT * (KT + 1)];   // padded stride 33: conflict-free
    __shared__ float a4row[OO];

    const float* arow = a_ws + (b * LL + l) * CC;
    for (int idx = t; idx < CC * OO; idx += 256)
        wl[idx] = arow[idx >> 6] * w3[idx];
    if (t < OO) a4row[t] = a4b3_ws[(b * LL + l) * OO + t];

    const int mg = t >> 3;      // 0..31 -> 4 m rows each
    const int og = t & 7;       // 0..7  -> 8 o cols each
    const int mbase = mc * MT;

    float acc[4][8];
#pragma unroll
    for (int i = 0; i < 4; ++i)
#pragma unroll
        for (int j = 0; j < 8; ++j) acc[i][j] = 0.0f;

    for (int k0 = 0; k0 < CC; k0 += KT) {
        __syncthreads();   // also guards wl/a4row writes before first use
        for (int idx = t; idx < MT * KT; idx += 256) {
            const int mi = idx >> 5;          // /KT
            const int ci = idx & (KT - 1);
            btile[mi * (KT + 1) + ci] = b_ws[(b * LL + mbase + mi) * CC + k0 + ci];
        }
        __syncthreads();
#pragma unroll
        for (int ci = 0; ci < KT; ++ci) {
            const float4 wv0 = *(const float4*)&wl[(k0 + ci) * OO + og * 8];
            const float4 wv1 = *(const float4*)&wl[(k0 + ci) * OO + og * 8 + 4];
#pragma unroll
            for (int i = 0; i < 4; ++i) {
                const float bv = btile[(mg * 4 + i) * (KT + 1) + ci];
                acc[i][0] = fmaf(bv, wv0.x, acc[i][0]);
                acc[i][1] = fmaf(bv, wv0.y, acc[i][1]);
                acc[i][2] = fmaf(bv, wv0.z, acc[i][2]);
                acc[i][3] = fmaf(bv, wv0.w, acc[i][3]);
                acc[i][4] = fmaf(bv, wv1.x, acc[i][4]);
                acc[i][5] = fmaf(bv, wv1.y, acc[i][5]);
                acc[i][6] = fmaf(bv, wv1.z, acc[i][6]);
                acc[i][7] = fmaf(bv, wv1.w, acc[i][7]);
            }
        }
    }

    const float4 a40 = *(const float4*)&a4row[og * 8];
    const float4 a41 = *(const float4*)&a4row[og * 8 + 4];
#pragma unroll
    for (int i = 0; i < 4; ++i) {
        const int m = mbase + mg * 4 + i;
        const float* b4p = b4_ws + (b * LL + m) * OO + og * 8;
        const float4 bq0 = *(const float4*)&b4p[0];
        const float4 bq1 = *(const float4*)&b4p[4];
        float4 r0, r1;
        r0.x = acc[i][0] + a40.x - bq0.x;
        r0.y = acc[i][1] + a40.y - bq0.y;
        r0.z = acc[i][2] + a40.z - bq0.z;
        r0.w = acc[i][3] + a40.w - bq0.w;
        r1.x = acc[i][4] + a41.x - bq1.x;
        r1.y = acc[i][5] + a41.y - bq1.y;
        r1.z = acc[i][6] + a41.z - bq1.z;
        r1.w = acc[i][7] + a41.w - bq1.w;
        float* op = out + (((size_t)(b * LL + l) * LL + m) * OO + og * 8);
        *(float4*)&op[0] = r0;
        *(float4*)&op[4] = r1;
    }
}

extern "C" void kernel_launch(void* const* d_in, const int* in_sizes, int n_in,
                              void* d_out, int out_size, void* d_ws, size_t ws_size,
                              hipStream_t stream) {
    const float* x     = (const float*)d_in[0];
    const float* gamma = (const float*)d_in[1];
    const float* beta  = (const float*)d_in[2];
    const float* w1    = (const float*)d_in[3];
    const float* b1    = (const float*)d_in[4];
    const float* w2    = (const float*)d_in[5];
    const float* b2    = (const float*)d_in[6];
    const float* w3    = (const float*)d_in[7];
    const float* b3    = (const float*)d_in[8];
    const float* w4    = (const float*)d_in[9];
    float* out = (float*)d_out;

    float* ws = (float*)d_ws;
    float* a_ws    = ws;                          // B*L*C
    float* b_ws    = ws + BB * LL * CC;           // B*L*C
    float* a4b3_ws = ws + 2 * BB * LL * CC;       // B*L*O
    float* b4_ws   = a4b3_ws + BB * LL * OO;      // B*L*O  (total 1.5 MB)

    prep_kernel<<<BB * LL, 256, 0, stream>>>(x, gamma, beta, w1, b1, w2, b2,
                                             w4, b3, a_ws, b_ws, a4b3_ws, b4_ws);
    main_kernel<<<BB * LL * 4, 256, 0, stream>>>(a_ws, b_ws, a4b3_ws, b4_ws,
                                                 w3, out);
}

// Round 2
// 187.600 us; speedup vs baseline: 1.5642x; 1.5642x over previous
//
#include <hip/hip_runtime.h>
#include <hip/hip_bf16.h>

// Problem constants: L=512, B=2, D=256, C=128, O=64
#define LL 512
#define BB 2
#define DD 256
#define CC 128
#define OO 64

#define WT_STRIDE 136   // 128 + 8 pad: 16B-aligned rows, <=2-way LDS banks

typedef __attribute__((ext_vector_type(8))) short bf16x8;  // 8 bf16 (4 VGPRs)
typedef __attribute__((ext_vector_type(4))) float f32x4;   // 4 fp32 acc

__device__ __forceinline__ short f2bf(float v) {
    __hip_bfloat16 h = __float2bfloat16(v);
    return *reinterpret_cast<short*>(&h);
}

__device__ __forceinline__ float wave_reduce_sum(float v) {
#pragma unroll
    for (int off = 32; off > 0; off >>= 1)
        v += __shfl_down(v, off, 64);
    return v;
}

// One block per (b, l): LayerNorm of x[l,b,:], then
//   a[c]    = LN(x).w1[:,c] + b1[c]      -> a_ws (fp32, for W_l build)
//   b[c]    = LN(x).w2[:,c] + b2[c]      -> bact (bf16, MFMA A-operand)
//   a4b3[o] = a.w4[:,o] + b3[o]          -> fp32
//   b4[o]   = b.w4[:,o]                  -> fp32
__global__ __launch_bounds__(256) void prep_kernel(
    const float* __restrict__ x,
    const float* __restrict__ gamma,
    const float* __restrict__ beta,
    const float* __restrict__ w1, const float* __restrict__ b1,
    const float* __restrict__ w2, const float* __restrict__ b2,
    const float* __restrict__ w4, const float* __restrict__ b3,
    float* __restrict__ a_ws, __hip_bfloat16* __restrict__ bact,
    float* __restrict__ a4b3_ws, float* __restrict__ b4_ws)
{
    const int blk = blockIdx.x;           // b*LL + l
    const int b = blk >> 9;
    const int l = blk & (LL - 1);
    const int t = threadIdx.x;            // 0..255 == d index

    __shared__ float ylds[DD];
    __shared__ float ab[2 * CC];
    __shared__ float red[8];

    // x is (L, B, D)
    float xv = x[(l * BB + b) * DD + t];
    float s = wave_reduce_sum(xv);
    if ((t & 63) == 0) red[t >> 6] = s;
    __syncthreads();
    float mu = (red[0] + red[1] + red[2] + red[3]) * (1.0f / DD);
    float xc = xv - mu;
    float s2 = wave_reduce_sum(xc * xc);
    if ((t & 63) == 0) red[4 + (t >> 6)] = s2;
    __syncthreads();
    float var = (red[4] + red[5] + red[6] + red[7]) * (1.0f / DD);
    float y = xc * rsqrtf(var + 1e-5f) * gamma[t] + beta[t];
    ylds[t] = y;
    __syncthreads();

    // a (threads 0..127) and b (threads 128..255) projections
    {
        const int c = t & (CC - 1);
        const float* w = (t < CC) ? w1 : w2;
        float acc = (t < CC) ? b1[c] : b2[c];
#pragma unroll 16
        for (int d = 0; d < DD; ++d)
            acc = fmaf(ylds[d], w[d * CC + c], acc);
        ab[t] = acc;
        if (t < CC) {
            a_ws[(b * LL + l) * CC + c] = acc;
        } else {
            bact[(b * LL + l) * CC + c] = __float2bfloat16(acc);
        }
    }
    __syncthreads();

    // a4+b3 (threads 0..63) and b4 (threads 64..127)
    if (t < 2 * OO) {
        const int o = t & (OO - 1);
        const float* src = (t < OO) ? ab : (ab + CC);
        float acc = (t < OO) ? b3[o] : 0.0f;
#pragma unroll 16
        for (int c = 0; c < CC; ++c)
            acc = fmaf(src[c], w4[c * OO + o], acc);
        float* dst = (t < OO) ? a4b3_ws : b4_ws;
        dst[(b * LL + l) * OO + o] = acc;
    }
}

// One block per (b, l, m-half). 4 waves; wave w computes out[b, l, mh*256+w*64 .. +64, :]
// via bf16 MFMA:  out = Bact(64x128) @ W_l(128x64),  W_l[c][o] = a[l,c]*w3[c,o],
// staged transposed in LDS as Wt[o][c] so B-fragments are contiguous.
__global__ __launch_bounds__(256, 3) void main_kernel(
    const float* __restrict__ a_ws, const __hip_bfloat16* __restrict__ bact,
    const float* __restrict__ a4b3_ws, const float* __restrict__ b4_ws,
    const float* __restrict__ w3,
    float* __restrict__ out)
{
    const int bid = blockIdx.x;           // b*1024 + l*2 + mh
    const int mh = bid & 1;
    const int l  = (bid >> 1) & (LL - 1);
    const int b  = bid >> 10;
    const int t  = threadIdx.x;
    const int wave = t >> 6;
    const int lane = t & 63;
    const int ln = lane & 15;             // col within 16x16 tile
    const int q  = lane >> 4;             // quad

    __shared__ short Wt[OO * WT_STRIDE];  // Wt[o][c] = bf16(a[l,c]*w3[c,o])

    // Build Wt: coalesced float4 reads of w3 (c-major, o contiguous)
    const float* arow = a_ws + (b * LL + l) * CC;
    const float4* w3v4 = (const float4*)w3;
#pragma unroll
    for (int i4 = t; i4 < CC * OO / 4; i4 += 256) {
        const int c = i4 >> 4;            // (i4*4) / 64
        const int o = (i4 & 15) * 4;
        const float ac = arow[c];
        const float4 wv = w3v4[i4];
        Wt[(o + 0) * WT_STRIDE + c] = f2bf(ac * wv.x);
        Wt[(o + 1) * WT_STRIDE + c] = f2bf(ac * wv.y);
        Wt[(o + 2) * WT_STRIDE + c] = f2bf(ac * wv.z);
        Wt[(o + 3) * WT_STRIDE + c] = f2bf(ac * wv.w);
    }
    __syncthreads();

    const int mbase = mh * 256 + wave * 64;

    // A-frag base: lane ln,q holds Bact[m = mbase+mt*16+ln][c = ks*32+q*8 .. +8]
    const short* abase = (const short*)bact + ((size_t)(b * LL + mbase + ln)) * CC + q * 8;
    // B-frag base: lane ln,q holds Wt[o = ot*16+ln][c = ks*32+q*8 .. +8]
    const short* wbase = &Wt[ln * WT_STRIDE + q * 8];

    f32x4 acc[4][4];
#pragma unroll
    for (int mt = 0; mt < 4; ++mt)
#pragma unroll
        for (int ot = 0; ot < 4; ++ot)
            acc[mt][ot] = (f32x4){0.f, 0.f, 0.f, 0.f};

#pragma unroll
    for (int ks = 0; ks < 4; ++ks) {
        bf16x8 af[4], bfr[4];
#pragma unroll
        for (int mt = 0; mt < 4; ++mt)
            af[mt] = *(const bf16x8*)(abase + mt * (16 * CC) + ks * 32);
#pragma unroll
        for (int ot = 0; ot < 4; ++ot)
            bfr[ot] = *(const bf16x8*)(wbase + ot * (16 * WT_STRIDE) + ks * 32);
#pragma unroll
        for (int mt = 0; mt < 4; ++mt)
#pragma unroll
            for (int ot = 0; ot < 4; ++ot)
                acc[mt][ot] = __builtin_amdgcn_mfma_f32_16x16x32_bf16(
                    af[mt], bfr[ot], acc[mt][ot], 0, 0, 0);
    }

    // Epilogue: out[b,l,m,o] = acc + a4b3[b,l,o] - b4[b,m,o]
    // C/D layout: col = lane&15, row = q*4 + reg   [verified m89/m91]
    float a4v[4];
    const float* a4p = a4b3_ws + (b * LL + l) * OO;
#pragma unroll
    for (int ot = 0; ot < 4; ++ot)
        a4v[ot] = a4p[ot * 16 + ln];

#pragma unroll
    for (int mt = 0; mt < 4; ++mt) {
        const int mrow = mbase + mt * 16 + q * 4;
        const float* b4p = b4_ws + ((size_t)(b * LL + mrow)) * OO + ln;
        float* outp = out + (((size_t)(b * LL + l)) * LL + mrow) * OO + ln;
#pragma unroll
        for (int ot = 0; ot < 4; ++ot) {
#pragma unroll
            for (int r = 0; r < 4; ++r) {
                outp[r * OO + ot * 16] = acc[mt][ot][r] + a4v[ot] - b4p[r * OO + ot * 16];
            }
        }
    }
}

extern "C" void kernel_launch(void* const* d_in, const int* in_sizes, int n_in,
                              void* d_out, int out_size, void* d_ws, size_t ws_size,
                              hipStream_t stream) {
    const float* x     = (const float*)d_in[0];
    const float* gamma = (const float*)d_in[1];
    const float* beta  = (const float*)d_in[2];
    const float* w1    = (const float*)d_in[3];
    const float* b1    = (const float*)d_in[4];
    const float* w2    = (const float*)d_in[5];
    const float* b2    = (const float*)d_in[6];
    const float* w3    = (const float*)d_in[7];
    const float* b3    = (const float*)d_in[8];
    const float* w4    = (const float*)d_in[9];
    float* out = (float*)d_out;

    char* ws = (char*)d_ws;
    float* a_ws            = (float*)ws;                      // B*L*C fp32   = 512 KB
    __hip_bfloat16* bact   = (__hip_bfloat16*)(ws + 512*1024); // B*L*C bf16  = 256 KB
    float* a4b3_ws         = (float*)(ws + 768*1024);          // B*L*O fp32  = 256 KB
    float* b4_ws           = (float*)(ws + 1024*1024);         // B*L*O fp32  = 256 KB

    prep_kernel<<<BB * LL, 256, 0, stream>>>(x, gamma, beta, w1, b1, w2, b2,
                                             w4, b3, a_ws, bact, a4b3_ws, b4_ws);
    main_kernel<<<BB * LL * 2, 256, 0, stream>>>(a_ws, bact, a4b3_ws, b4_ws,
                                                 w3, out);
}